// Round 12
// baseline (705.758 us; speedup 1.0000x reference)
//
#include <hip/hip_runtime.h>
#include <hip/hip_bf16.h>
#include <stdint.h>

#define T_TOK 2048
#define HDIM  1024
#define IDIM  768
#define NEXP  32
#define TOPK  4
#define NPAIR (T_TOK*TOPK)   // 8192

typedef __attribute__((ext_vector_type(8))) short bf16x8;
typedef __attribute__((ext_vector_type(4))) float f32x4;

__device__ __forceinline__ unsigned short f2bf(float f){
  union { float f; unsigned u; } v; v.f = f;
  unsigned r = (v.u + 0x7fffu + ((v.u >> 16) & 1u)) >> 16;  // RNE
  return (unsigned short)r;
}

__device__ __forceinline__ unsigned pack_bf2(float lo, float hi){
  __hip_bfloat162 h2 = __float22bfloat162_rn(float2{lo, hi});  // v_cvt_pk_bf16_f32
  union { __hip_bfloat162 h; unsigned u; } v; v.h = h2;
  return v.u;
}

__device__ __forceinline__ f32x4 ntload4(const void* p){
  return __builtin_nontemporal_load((const f32x4*)p);
}

// ---------------- x fp32 -> bf16 ----------------
__global__ __launch_bounds__(256) void k_convert_x(const float* __restrict__ x,
                                                   ushort* __restrict__ xb){
  int idx = blockIdx.x*256 + threadIdx.x;
  float4 v = ((const float4*)x)[idx];
  ushort4 o; o.x=f2bf(v.x); o.y=f2bf(v.y); o.z=f2bf(v.z); o.w=f2bf(v.w);
  ((ushort4*)xb)[idx] = o;
}

// ---------------- router ----------------
__global__ __launch_bounds__(256) void k_router(const float* __restrict__ x,
                                                const float* __restrict__ gw,
                                                int* __restrict__ ei, float* __restrict__ wv,
                                                int* __restrict__ counts){
  int wid  = threadIdx.x >> 6;
  int lane = threadIdx.x & 63;
  int t = blockIdx.x*4 + wid;
  float xv[16];
  #pragma unroll
  for (int i=0;i<16;i++) xv[i] = x[t*HDIM + i*64 + lane];
  float p[NEXP];
  #pragma unroll
  for (int e=0;e<NEXP;e++){
    const float* w = gw + e*HDIM;
    float a = 0.f;
    #pragma unroll
    for (int i=0;i<16;i++) a = fmaf(xv[i], w[i*64+lane], a);
    #pragma unroll
    for (int off=32; off>=1; off>>=1) a += __shfl_xor(a, off, 64);
    p[e] = a;
  }
  float m = p[0];
  #pragma unroll
  for (int e=1;e<NEXP;e++) m = fmaxf(m, p[e]);
  #pragma unroll
  for (int e=0;e<NEXP;e++) p[e] = __expf(p[e]-m);
  unsigned used = 0; int sel[TOPK]; float sw[TOPK]; float wsum = 0.f;
  #pragma unroll
  for (int k=0;k<TOPK;k++){
    float best = -1.f; int bi = 0;
    #pragma unroll
    for (int e=0;e<NEXP;e++){
      bool ok = (((used>>e)&1u)==0u) && (p[e] > best);
      best = ok ? p[e] : best; bi = ok ? e : bi;
    }
    used |= 1u<<bi; sel[k]=bi; sw[k]=best; wsum += best;
  }
  if (lane==0){
    float inv = 1.f/wsum;
    #pragma unroll
    for (int k=0;k<TOPK;k++){
      ei[t*TOPK+k] = sel[k];
      wv[t*TOPK+k] = sw[k]*inv;
      atomicAdd(&counts[sel[k]], 1);
    }
  }
}

// ---------------- offsets ----------------
__global__ void k_offsets(const int* __restrict__ counts, int* __restrict__ offsets){
  if (threadIdx.x==0 && blockIdx.x==0){
    int s=0;
    for (int e=0;e<NEXP;e++){ offsets[e]=s; s+=counts[e]; }
    offsets[NEXP]=s;
  }
}

__global__ __launch_bounds__(256) void k_scatter(const int* __restrict__ ei,
                                                 const int* __restrict__ offsets,
                                                 int* __restrict__ cursor,
                                                 int* __restrict__ slot_tk,
                                                 int* __restrict__ tk_slot){
  int g = blockIdx.x*256 + threadIdx.x;
  int e = ei[g];
  int pos = atomicAdd(&cursor[e], 1);
  int slot = offsets[e] + pos;
  slot_tk[slot] = g;
  tk_slot[g] = slot;
}

// ---------------- gate+up GEMM, fused SiLU ----------------
// Block = (expert, it) covering i-rows [it*16, it*16+16) of BOTH w1 and w3.
// Stage: contiguous full-row nt-loads -> bf16 LDS (XOR-swizzled), 1 barrier.
// Consume: A direct from L2-resident xb; out = silu(g)*u -> act3 (tile-major).
__global__ __launch_bounds__(512,4) void k_gateup(const ushort* __restrict__ xb,
    const float* __restrict__ w1, const float* __restrict__ w3,
    const int* __restrict__ offsets, const int* __restrict__ slot_tk,
    ushort* __restrict__ act3){
  int bi  = blockIdx.x;                   // 1536
  int xcd = bi & 7, j = bi >> 3;          // same-expert blocks -> same XCD, consecutive
  int e   = xcd + 8*(j/48);
  int it  = j % 48;
  int off0 = offsets[e], ne = offsets[e+1]-off0;
  if (ne == 0) return;
  int ibase = it*16;

  __shared__ ushort B[32][1024];          // rows 0-15: w1, 16-31: w3; 16B-chunk XOR swizzle

  int tid = threadIdx.x, wid = tid>>6, lane = tid&63;

  // ---- stage: wave w -> 4 full rows, contiguous nt reads ----
  {
    const float* msrc = (wid < 4) ? w1 : w3;
    int r0 = (wid&3)*4;
    const char* src = (const char*)(msrc + (size_t)e*IDIM*HDIM + (size_t)(ibase+r0)*HDIM);
    f32x4 st[4][4];
    #pragma unroll
    for (int r=0;r<4;r++){
      const char* rp = src + (size_t)r*4096;
      st[r][0] = ntload4(rp + lane*32);
      st[r][1] = ntload4(rp + lane*32 + 16);
      st[r][2] = ntload4(rp + 2048 + lane*32);
      st[r][3] = ntload4(rp + 2048 + lane*32 + 16);
    }
    #pragma unroll
    for (int r=0;r<4;r++){
      int row = (wid>>2)*16 + r0 + r;
      uint4 c0, c1;
      c0.x=pack_bf2(st[r][0][0],st[r][0][1]); c0.y=pack_bf2(st[r][0][2],st[r][0][3]);
      c0.z=pack_bf2(st[r][1][0],st[r][1][1]); c0.w=pack_bf2(st[r][1][2],st[r][1][3]);
      c1.x=pack_bf2(st[r][2][0],st[r][2][1]); c1.y=pack_bf2(st[r][2][2],st[r][2][3]);
      c1.z=pack_bf2(st[r][3][0],st[r][3][1]); c1.w=pack_bf2(st[r][3][2],st[r][3][3]);
      char* rowb = (char*)&B[row][0];
      *(uint4*)(rowb + ((lane     ) ^ (row&7))*16) = c0;
      *(uint4*)(rowb + ((lane + 64) ^ (row&7))*16) = c1;
    }
  }
  __syncthreads();

  // ---- consume: M=128 per pass ----
  int q = lane >> 4;
  for (int m0 = 0; m0 < ne; m0 += 128){
    int rowid = m0 + wid*16 + (lane&15);
    int slotc = off0 + (rowid < ne ? rowid : ne-1);
    int tok = slot_tk[slotc] >> 2;
    f32x4 accg = {0,0,0,0}, accu = {0,0,0,0};
    #pragma unroll
    for (int kh=0; kh<2; kh++){
      bf16x8 a[16];
      const ushort* ap = xb + (size_t)tok*HDIM + kh*512 + q*8;
      #pragma unroll
      for (int s=0;s<16;s++) a[s] = *(const bf16x8*)(ap + s*32);
      #pragma unroll
      for (int s=0;s<16;s++){
        int c = kh*64 + s*4 + q;
        int rg = lane&15;
        bf16x8 bg = *(const bf16x8*)((const char*)&B[rg][0] + ((c ^ (rg&7))*16));
        int ru = 16 + (lane&15);
        bf16x8 bu = *(const bf16x8*)((const char*)&B[ru][0] + ((c ^ (ru&7))*16));
        accg = __builtin_amdgcn_mfma_f32_16x16x32_bf16(a[s], bg, accg, 0,0,0);
        accu = __builtin_amdgcn_mfma_f32_16x16x32_bf16(a[s], bu, accu, 0,0,0);
      }
    }
    #pragma unroll
    for (int r=0;r<4;r++){
      int row = m0 + wid*16 + q*4 + r;
      if (row < ne){
        float g = accg[r], u = accu[r];
        float sval = g / (1.f + __expf(-g)) * u;
        act3[((size_t)it*NPAIR + off0 + row)*16 + (lane&15)] = f2bf(sval);
      }
    }
  }
}

// ---------------- down GEMM ----------------
// Block = (expert, ht) covering h-rows [ht*32, +32). Same streaming structure.
// A from act3 (tile-major, L2-hot); out -> pout3 (tile-major, dense lines).
__global__ __launch_bounds__(512,4) void k_down(const ushort* __restrict__ act3,
    const float* __restrict__ w2, const int* __restrict__ offsets,
    const int* __restrict__ slot_tk, float* __restrict__ pout3){
  int bi  = blockIdx.x;                   // 1024
  int xcd = bi & 7, j = bi >> 3;
  int e   = xcd + 8*(j/32);
  int ht  = j % 32;
  int off0 = offsets[e], ne = offsets[e+1]-off0;
  if (ne == 0) return;
  int hbase = ht*32;

  __shared__ ushort B[32][768];

  int tid = threadIdx.x, wid = tid>>6, lane = tid&63;

  // ---- stage: wave w -> rows 4w..4w+3 = 12 KB contiguous nt reads ----
  {
    const char* rp = (const char*)(w2 + (size_t)e*HDIM*IDIM + (size_t)(hbase + wid*4)*IDIM);
    f32x4 st[6][2];
    #pragma unroll
    for (int w2i=0; w2i<6; w2i++){
      st[w2i][0] = ntload4(rp + w2i*2048 + lane*32);
      st[w2i][1] = ntload4(rp + w2i*2048 + lane*32 + 16);
    }
    #pragma unroll
    for (int w2i=0; w2i<6; w2i++){
      int cg = w2i*64 + lane;               // 32B chunk within 4-row group
      int rl = (cg >= 288) ? 3 : (cg >= 192) ? 2 : (cg >= 96) ? 1 : 0;
      int c  = cg - rl*96;                  // 16B bf16 chunk within row
      int row = wid*4 + rl;
      uint4 cc;
      cc.x=pack_bf2(st[w2i][0][0],st[w2i][0][1]); cc.y=pack_bf2(st[w2i][0][2],st[w2i][0][3]);
      cc.z=pack_bf2(st[w2i][1][0],st[w2i][1][1]); cc.w=pack_bf2(st[w2i][1][2],st[w2i][1][3]);
      *(uint4*)((char*)&B[row][0] + ((c ^ (row&7))*16)) = cc;
    }
  }
  __syncthreads();

  // ---- consume ----
  int q = lane >> 4;
  for (int m0 = 0; m0 < ne; m0 += 128){
    int rowid = m0 + wid*16 + (lane&15);
    int slotc = off0 + (rowid < ne ? rowid : ne-1);
    f32x4 acc0 = {0,0,0,0}, acc1 = {0,0,0,0};
    #pragma unroll
    for (int kh=0; kh<2; kh++){
      bf16x8 a[12];
      #pragma unroll
      for (int s=0;s<12;s++){
        int c = kh*48 + s*4 + q;            // 16B chunk in [0,96)
        a[s] = *(const bf16x8*)(act3 + ((size_t)(c>>1)*NPAIR + slotc)*16 + (c&1)*8);
      }
      #pragma unroll
      for (int s=0;s<12;s++){
        int c = kh*48 + s*4 + q;
        int r0 = lane&15;
        bf16x8 b0 = *(const bf16x8*)((const char*)&B[r0][0] + ((c ^ (r0&7))*16));
        int r1 = 16 + (lane&15);
        bf16x8 b1 = *(const bf16x8*)((const char*)&B[r1][0] + ((c ^ (r1&7))*16));
        acc0 = __builtin_amdgcn_mfma_f32_16x16x32_bf16(a[s], b0, acc0, 0,0,0);
        acc1 = __builtin_amdgcn_mfma_f32_16x16x32_bf16(a[s], b1, acc1, 0,0,0);
      }
    }
    #pragma unroll
    for (int r=0;r<4;r++){
      int row = m0 + wid*16 + q*4 + r;
      if (row < ne){
        size_t base = ((size_t)ht*NPAIR + off0 + row)*32 + (lane&15);
        pout3[base     ] = acc0[r];
        pout3[base + 16] = acc1[r];
      }
    }
  }
}

// ---------------- combine ----------------
__global__ __launch_bounds__(256) void k_combine(const float* __restrict__ pout3,
    const int* __restrict__ tk_slot, const float* __restrict__ wv,
    float* __restrict__ out){
  int t = blockIdx.x;
  int c = threadIdx.x;                 // h = c*4
  int h0 = c*4;
  float a0=0,a1=0,a2=0,a3=0;
  #pragma unroll
  for (int k=0;k<TOPK;k++){
    int slot = tk_slot[t*TOPK+k];
    float w  = wv[t*TOPK+k];
    const float* p = pout3 + ((size_t)(h0>>5)*NPAIR + slot)*32 + (h0&31);
    float4 v = *(const float4*)p;
    a0 = fmaf(w, v.x, a0); a1 = fmaf(w, v.y, a1);
    a2 = fmaf(w, v.z, a2); a3 = fmaf(w, v.w, a3);
  }
  float4 o; o.x=a0; o.y=a1; o.z=a2; o.w=a3;
  *(float4*)(out + (size_t)t*HDIM + h0) = o;
}

extern "C" void kernel_launch(void* const* d_in, const int* in_sizes, int n_in,
                              void* d_out, int out_size, void* d_ws, size_t ws_size,
                              hipStream_t stream){
  const float* x  = (const float*)d_in[0];
  const float* gw = (const float*)d_in[1];
  const float* w1 = (const float*)d_in[2];
  const float* w3 = (const float*)d_in[3];
  const float* w2 = (const float*)d_in[4];
  float* out = (float*)d_out;

  char* ws = (char*)d_ws;
  size_t off = 0;
  ushort* xb   = (ushort*)(ws + off); off += (size_t)T_TOK*HDIM*2;       // 4 MB
  ushort* act3 = (ushort*)(ws + off); off += (size_t)48*NPAIR*16*2;      // 12.6 MB
  float*  pout3= (float*) (ws + off); off += (size_t)32*NPAIR*32*4;      // 33.6 MB
  int* counts  = (int*)(ws + off); off += NEXP*4;
  int* cursor  = (int*)(ws + off); off += NEXP*4;
  int* offsets = (int*)(ws + off); off += (NEXP+1)*4;
  off = (off + 255) & ~(size_t)255;
  int*   ei      = (int*)  (ws + off); off += (size_t)NPAIR*4;
  float* wvp     = (float*)(ws + off); off += (size_t)NPAIR*4;
  int*   slot_tk = (int*)  (ws + off); off += (size_t)NPAIR*4;
  int*   tk_slot = (int*)  (ws + off); off += (size_t)NPAIR*4;

  hipMemsetAsync(counts, 0, 2*NEXP*4, stream);

  k_convert_x<<<T_TOK*HDIM/1024, 256, 0, stream>>>(x, xb);
  k_router<<<T_TOK/4, 256, 0, stream>>>(x, gw, ei, wvp, counts);
  k_offsets<<<1, 64, 0, stream>>>(counts, offsets);
  k_scatter<<<NPAIR/256, 256, 0, stream>>>(ei, offsets, cursor, slot_tk, tk_slot);
  k_gateup<<<1536, 512, 0, stream>>>(xb, w1, w3, offsets, slot_tk, act3);
  k_down<<<1024, 512, 0, stream>>>(act3, w2, offsets, slot_tk, pout3);
  k_combine<<<T_TOK, 256, 0, stream>>>(pout3, tk_slot, wvp, out);
}

// Round 13
// 223.229 us; speedup vs baseline: 3.1616x; 3.1616x over previous
//
#include <hip/hip_runtime.h>
#include <hip/hip_bf16.h>
#include <stdint.h>

#define T_TOK 2048
#define HDIM  1024
#define IDIM  768
#define NEXP  32
#define TOPK  4
#define NPAIR (T_TOK*TOPK)   // 8192
#define MTILE 384
#define MAXMT 64

typedef __attribute__((ext_vector_type(8))) short bf16x8;
typedef __attribute__((ext_vector_type(4))) float f32x4;

#define SBAR0() __builtin_amdgcn_sched_barrier(0)
#define LBAR()  do{ asm volatile("s_waitcnt lgkmcnt(0)" ::: "memory"); \
                    __builtin_amdgcn_s_barrier(); SBAR0(); }while(0)

__device__ __forceinline__ unsigned short f2bf(float f){
  union { float f; unsigned u; } v; v.f = f;
  unsigned r = (v.u + 0x7fffu + ((v.u >> 16) & 1u)) >> 16;  // RNE
  return (unsigned short)r;
}

__device__ __forceinline__ unsigned pack_bf2(float lo, float hi){
  __hip_bfloat162 h2 = __float22bfloat162_rn(float2{lo, hi});  // v_cvt_pk_bf16_f32
  union { __hip_bfloat162 h; unsigned u; } v; v.h = h2;
  return v.u;
}

// ---------------- router (+ fused x->bf16 conversion) ----------------
__global__ __launch_bounds__(256) void k_router(const float* __restrict__ x,
                                                const float* __restrict__ gw,
                                                int* __restrict__ ei, float* __restrict__ wv,
                                                int* __restrict__ counts,
                                                ushort* __restrict__ xb){
  int wid  = threadIdx.x >> 6;
  int lane = threadIdx.x & 63;
  int t = blockIdx.x*4 + wid;
  float xv[16];
  #pragma unroll
  for (int i=0;i<16;i++) xv[i] = x[t*HDIM + i*64 + lane];
  float p[NEXP];
  #pragma unroll
  for (int e=0;e<NEXP;e++){
    const float* w = gw + e*HDIM;
    float a = 0.f;
    #pragma unroll
    for (int i=0;i<16;i++) a = fmaf(xv[i], w[i*64+lane], a);
    #pragma unroll
    for (int off=32; off>=1; off>>=1) a += __shfl_xor(a, off, 64);
    p[e] = a;
  }
  float m = p[0];
  #pragma unroll
  for (int e=1;e<NEXP;e++) m = fmaxf(m, p[e]);
  #pragma unroll
  for (int e=0;e<NEXP;e++) p[e] = __expf(p[e]-m);
  unsigned used = 0; int sel[TOPK]; float sw[TOPK]; float wsum = 0.f;
  #pragma unroll
  for (int k=0;k<TOPK;k++){
    float best = -1.f; int bi = 0;
    #pragma unroll
    for (int e=0;e<NEXP;e++){
      bool ok = (((used>>e)&1u)==0u) && (p[e] > best);
      best = ok ? p[e] : best; bi = ok ? e : bi;
    }
    used |= 1u<<bi; sel[k]=bi; sw[k]=best; wsum += best;
  }
  if (lane==0){
    float inv = 1.f/wsum;
    #pragma unroll
    for (int k=0;k<TOPK;k++){
      ei[t*TOPK+k] = sel[k];
      wv[t*TOPK+k] = sw[k]*inv;
      atomicAdd(&counts[sel[k]], 1);
    }
  }
  // fused conversion of this wave's token row
  #pragma unroll
  for (int kq=0;kq<4;kq++){
    float4 v = *(const float4*)(x + (size_t)t*HDIM + (kq*64+lane)*4);
    ushort4 o; o.x=f2bf(v.x); o.y=f2bf(v.y); o.z=f2bf(v.z); o.w=f2bf(v.w);
    *(ushort4*)(xb + (size_t)t*HDIM + (kq*64+lane)*4) = o;
  }
}

// ---------------- offsets + m-tile worklist ----------------
__global__ void k_offsets(const int* __restrict__ counts, int* __restrict__ offsets,
                          int* __restrict__ mtE, int* __restrict__ mtM0,
                          int* __restrict__ nmt){
  if (threadIdx.x==0 && blockIdx.x==0){
    int s=0;
    for (int e=0;e<NEXP;e++){ offsets[e]=s; s+=counts[e]; }
    offsets[NEXP]=s;
    int nm=0;
    for (int e=0;e<NEXP;e++){
      int ne = counts[e];
      for (int m0=0; m0<ne && nm<MAXMT; m0+=MTILE){ mtE[nm]=e; mtM0[nm]=m0; nm++; }
    }
    nmt[0]=nm;
  }
}

__global__ __launch_bounds__(256) void k_scatter(const int* __restrict__ ei,
                                                 const int* __restrict__ offsets,
                                                 int* __restrict__ cursor,
                                                 int* __restrict__ slot_tk,
                                                 int* __restrict__ tk_slot){
  int g = blockIdx.x*256 + threadIdx.x;
  int e = ei[g];
  int pos = atomicAdd(&cursor[e], 1);
  int slot = offsets[e] + pos;
  slot_tk[slot] = g;
  tk_slot[g] = slot;
}

// ---------------- gate+up GEMM + SiLU ----------------
// M=384 x N=32 (x2 mats). K=1024 = 16 steps of 64.
// 3-deep LDS ring + 3 breg sets: writeB(h+1) reads a set loaded at h-2
// (2 iterations of HBM-latency cover). A in regs, distance 1 (L2).
// FIFO: per iter issue loadA THEN loadB, so A-wait never drains B(h+3).
__global__ __launch_bounds__(512,4) void k_gateup(const ushort* __restrict__ xb,
    const float* __restrict__ w1, const float* __restrict__ w3,
    const int* __restrict__ offsets, const int* __restrict__ slot_tk,
    const int* __restrict__ mtE, const int* __restrict__ mtM0, const int* __restrict__ nmt,
    ushort* __restrict__ act){
  const int NHS = 16;
  int bi  = blockIdx.x;               // 1536
  int s   = bi >> 3;
  int mti = (s/24)*8 + (bi&7);
  int it  = s % 24;
  if (mti >= nmt[0]) return;
  int e    = mtE[mti];
  int m0   = mtM0[mti];
  int off0 = offsets[e];
  int ne   = offsets[e+1]-off0;
  int ibase = it*32;

  __shared__ ushort Bls[3][64][72];    // [buf][mat*32+irow][64 bf16 + 8 pad]
  __shared__ int toks[MTILE];

  int tid = threadIdx.x, wid = tid>>6, lane = tid&63;
  if (tid < MTILE){
    int slot = off0 + m0 + tid;
    int fb = slot_tk[off0] >> 2;
    toks[tid] = (m0 + tid < ne) ? (slot_tk[slot] >> 2) : fb;
  }
  __syncthreads();

  // B staging: 64 rows x 64 f32 per step; 2 rounds of (32 rows x 16 lanes x 16B)
  const float* bp[2]; int brow_s[2];
  #pragma unroll
  for (int ss=0;ss<2;ss++){
    int row = ss*32 + wid*4 + (lane>>4);   // 0..63
    brow_s[ss] = row;
    int mat = row>>5, ir = row&31;
    bp[ss] = (mat ? w3 : w1) + (size_t)e*IDIM*HDIM
           + (size_t)(ibase+ir)*HDIM + (lane&15)*4;
  }
  int q = lane>>4;
  const ushort* arow[3];
  #pragma unroll
  for (int m=0;m<3;m++){
    int row = wid*48 + m*16 + (lane&15);
    arow[m] = xb + (size_t)toks[row]*HDIM + q*8;
  }

  f32x4 accg[3][2], accu[3][2];
  #pragma unroll
  for (int m=0;m<3;m++)
    #pragma unroll
    for (int n=0;n<2;n++){ accg[m][n]=(f32x4){0,0,0,0}; accu[m][n]=(f32x4){0,0,0,0}; }

  float4 b0[2], b1[2], b2[2];
  bf16x8 aA[3][2];

  auto loadB = [&](int t, float4 (&d)[2]){
    d[0] = *(const float4*)(bp[0] + t*64);
    d[1] = *(const float4*)(bp[1] + t*64);
  };
  auto writeB = [&](int buf, const float4 (&sv)[2]){
    #pragma unroll
    for (int ss=0;ss<2;ss++){
      uint2 u; u.x = pack_bf2(sv[ss].x, sv[ss].y); u.y = pack_bf2(sv[ss].z, sv[ss].w);
      *(uint2*)(&Bls[buf][brow_s[ss]][(lane&15)*4]) = u;
    }
  };
  auto loadA = [&](int t){
    #pragma unroll
    for (int m=0;m<3;m++)
      #pragma unroll
      for (int kk=0;kk<2;kk++)
        aA[m][kk] = *(const bf16x8*)(arow[m] + t*64 + kk*32);
  };
  auto computeK = [&](int buf){
    #pragma unroll
    for (int kk=0;kk<2;kk++){
      #pragma unroll
      for (int nf=0;nf<2;nf++){
        bf16x8 bg = *(const bf16x8*)(&Bls[buf][     nf*16 + (lane&15)][kk*32 + q*8]);
        bf16x8 bu = *(const bf16x8*)(&Bls[buf][32 + nf*16 + (lane&15)][kk*32 + q*8]);
        #pragma unroll
        for (int m=0;m<3;m++){
          accg[m][nf] = __builtin_amdgcn_mfma_f32_16x16x32_bf16(aA[m][kk], bg, accg[m][nf], 0,0,0);
          accu[m][nf] = __builtin_amdgcn_mfma_f32_16x16x32_bf16(aA[m][kk], bu, accu[m][nf], 0,0,0);
        }
      }
    }
  };

  // prologue: B(0),B(1),B(2) issued; LDS0 = B(0); A(0) in regs
  loadB(0, b0);
  loadA(0);
  loadB(1, b1);
  writeB(0, b0);               // waits only B(0) (oldest)
  loadB(2, b2);
  LBAR();

#define GUSTEP(h, cb, wb, BW, BL) \
  computeK(cb); \
  if ((h)+1 < NHS) loadA((h)+1); \
  if ((h)+3 < NHS) loadB((h)+3, BL); \
  if ((h)+1 < NHS) writeB(wb, BW); \
  LBAR();

  GUSTEP(0, 0, 1, b1, b0)  GUSTEP(1, 1, 2, b2, b1)  GUSTEP(2, 2, 0, b0, b2)
  GUSTEP(3, 0, 1, b1, b0)  GUSTEP(4, 1, 2, b2, b1)  GUSTEP(5, 2, 0, b0, b2)
  GUSTEP(6, 0, 1, b1, b0)  GUSTEP(7, 1, 2, b2, b1)  GUSTEP(8, 2, 0, b0, b2)
  GUSTEP(9, 0, 1, b1, b0)  GUSTEP(10,1, 2, b2, b1)  GUSTEP(11,2, 0, b0, b2)
  GUSTEP(12,0, 1, b1, b0)  GUSTEP(13,1, 2, b2, b1)  GUSTEP(14,2, 0, b0, b2)
  GUSTEP(15,0, 1, b1, b0)
#undef GUSTEP

  int nval = ne - m0; if (nval > MTILE) nval = MTILE;
  #pragma unroll
  for (int m=0;m<3;m++)
    #pragma unroll
    for (int nf=0;nf<2;nf++)
      #pragma unroll
      for (int r=0;r<4;r++){
        int row = wid*48 + m*16 + (lane>>4)*4 + r;
        if (row < nval){
          float g = accg[m][nf][r], u = accu[m][nf][r];
          float sval = g / (1.f + __expf(-g)) * u;
          act[(size_t)(off0+m0+row)*IDIM + ibase + nf*16 + (lane&15)] = f2bf(sval);
        }
      }
}

// ---------------- down GEMM ----------------
// M=384 x N=64. K=768 = 12 steps of 64. Same 3-ring pipeline.
__global__ __launch_bounds__(512,4) void k_down(const ushort* __restrict__ act,
    const float* __restrict__ w2, const int* __restrict__ offsets,
    const int* __restrict__ mtE, const int* __restrict__ mtM0, const int* __restrict__ nmt,
    float* __restrict__ pout){
  const int NHS = 12;
  int bi  = blockIdx.x;               // 1024
  int s   = bi >> 3;
  int mti = (s>>4)*8 + (bi&7);
  int ht  = s & 15;
  if (mti >= nmt[0]) return;
  int e    = mtE[mti];
  int m0   = mtM0[mti];
  int off0 = offsets[e], ne = offsets[e+1]-off0;
  int hbase = ht*64;

  __shared__ ushort Bls[3][64][72];

  int tid = threadIdx.x, wid = tid>>6, lane = tid&63;

  const float* bp[2]; int brow_s[2];
  #pragma unroll
  for (int ss=0;ss<2;ss++){
    int row = ss*32 + wid*4 + (lane>>4);
    brow_s[ss] = row;
    bp[ss] = w2 + (size_t)e*HDIM*IDIM + (size_t)(hbase+row)*IDIM + (lane&15)*4;
  }
  int q = lane>>4;
  const ushort* arow[3];
  #pragma unroll
  for (int m=0;m<3;m++){
    int row = m0 + wid*48 + m*16 + (lane&15);
    row = (row < ne) ? row : (ne-1);
    arow[m] = act + (size_t)(off0+row)*IDIM + q*8;
  }

  f32x4 acc[3][4];
  #pragma unroll
  for (int m=0;m<3;m++)
    #pragma unroll
    for (int n=0;n<4;n++) acc[m][n]=(f32x4){0,0,0,0};

  float4 b0[2], b1[2], b2[2];
  bf16x8 aA[3][2];

  auto loadB = [&](int t, float4 (&d)[2]){
    d[0] = *(const float4*)(bp[0] + t*64);
    d[1] = *(const float4*)(bp[1] + t*64);
  };
  auto writeB = [&](int buf, const float4 (&sv)[2]){
    #pragma unroll
    for (int ss=0;ss<2;ss++){
      uint2 u; u.x = pack_bf2(sv[ss].x, sv[ss].y); u.y = pack_bf2(sv[ss].z, sv[ss].w);
      *(uint2*)(&Bls[buf][brow_s[ss]][(lane&15)*4]) = u;
    }
  };
  auto loadA = [&](int t){
    #pragma unroll
    for (int m=0;m<3;m++)
      #pragma unroll
      for (int kk=0;kk<2;kk++)
        aA[m][kk] = *(const bf16x8*)(arow[m] + t*64 + kk*32);
  };
  auto computeK = [&](int buf){
    #pragma unroll
    for (int kk=0;kk<2;kk++){
      #pragma unroll
      for (int nf=0;nf<4;nf++){
        bf16x8 bw = *(const bf16x8*)(&Bls[buf][nf*16 + (lane&15)][kk*32 + q*8]);
        #pragma unroll
        for (int m=0;m<3;m++)
          acc[m][nf] = __builtin_amdgcn_mfma_f32_16x16x32_bf16(aA[m][kk], bw, acc[m][nf], 0,0,0);
      }
    }
  };

  loadB(0, b0);
  loadA(0);
  loadB(1, b1);
  writeB(0, b0);
  loadB(2, b2);
  LBAR();

#define DNSTEP(h, cb, wb, BW, BL) \
  computeK(cb); \
  if ((h)+1 < NHS) loadA((h)+1); \
  if ((h)+3 < NHS) loadB((h)+3, BL); \
  if ((h)+1 < NHS) writeB(wb, BW); \
  LBAR();

  DNSTEP(0, 0, 1, b1, b0)  DNSTEP(1, 1, 2, b2, b1)  DNSTEP(2, 2, 0, b0, b2)
  DNSTEP(3, 0, 1, b1, b0)  DNSTEP(4, 1, 2, b2, b1)  DNSTEP(5, 2, 0, b0, b2)
  DNSTEP(6, 0, 1, b1, b0)  DNSTEP(7, 1, 2, b2, b1)  DNSTEP(8, 2, 0, b0, b2)
  DNSTEP(9, 0, 1, b1, b0)  DNSTEP(10,1, 2, b2, b1)  DNSTEP(11,2, 0, b0, b2)
#undef DNSTEP

  int nval = ne - m0; if (nval > MTILE) nval = MTILE;
  #pragma unroll
  for (int m=0;m<3;m++)
    #pragma unroll
    for (int nf=0;nf<4;nf++)
      #pragma unroll
      for (int r=0;r<4;r++){
        int row = wid*48 + m*16 + (lane>>4)*4 + r;
        if (row < nval)
          pout[(size_t)(off0+m0+row)*HDIM + hbase + nf*16 + (lane&15)] = acc[m][nf][r];
      }
}

// ---------------- combine ----------------
__global__ __launch_bounds__(256) void k_combine(const float* __restrict__ pout,
    const int* __restrict__ tk_slot, const float* __restrict__ wv,
    float* __restrict__ out){
  int t = blockIdx.x;
  int c = threadIdx.x;
  float a0=0,a1=0,a2=0,a3=0;
  #pragma unroll
  for (int k=0;k<TOPK;k++){
    int slot = tk_slot[t*TOPK+k];
    float w  = wv[t*TOPK+k];
    float4 v = *(const float4*)(pout + (size_t)slot*HDIM + c*4);
    a0 = fmaf(w, v.x, a0); a1 = fmaf(w, v.y, a1);
    a2 = fmaf(w, v.z, a2); a3 = fmaf(w, v.w, a3);
  }
  float4 o; o.x=a0; o.y=a1; o.z=a2; o.w=a3;
  *(float4*)(out + (size_t)t*HDIM + c*4) = o;
}

extern "C" void kernel_launch(void* const* d_in, const int* in_sizes, int n_in,
                              void* d_out, int out_size, void* d_ws, size_t ws_size,
                              hipStream_t stream){
  const float* x  = (const float*)d_in[0];
  const float* gw = (const float*)d_in[1];
  const float* w1 = (const float*)d_in[2];
  const float* w3 = (const float*)d_in[3];
  const float* w2 = (const float*)d_in[4];
  float* out = (float*)d_out;

  char* ws = (char*)d_ws;
  size_t off = 0;
  ushort* xb   = (ushort*)(ws + off); off += (size_t)T_TOK*HDIM*2;
  ushort* act  = (ushort*)(ws + off); off += (size_t)NPAIR*IDIM*2;
  float*  pout = (float*) (ws + off); off += (size_t)NPAIR*HDIM*4;
  int* counts  = (int*)(ws + off); off += NEXP*4;
  int* cursor  = (int*)(ws + off); off += NEXP*4;
  int* offsets = (int*)(ws + off); off += (NEXP+1)*4;
  int* mtE     = (int*)(ws + off); off += MAXMT*4;
  int* mtM0    = (int*)(ws + off); off += MAXMT*4;
  int* nmt     = (int*)(ws + off); off += 4;
  off = (off + 255) & ~(size_t)255;
  int*   ei      = (int*)  (ws + off); off += (size_t)NPAIR*4;
  float* wvp     = (float*)(ws + off); off += (size_t)NPAIR*4;
  int*   slot_tk = (int*)  (ws + off); off += (size_t)NPAIR*4;
  int*   tk_slot = (int*)  (ws + off); off += (size_t)NPAIR*4;

  hipMemsetAsync(counts, 0, 2*NEXP*4, stream);

  k_router<<<T_TOK/4, 256, 0, stream>>>(x, gw, ei, wvp, counts, xb);
  k_offsets<<<1, 64, 0, stream>>>(counts, offsets, mtE, mtM0, nmt);
  k_scatter<<<NPAIR/256, 256, 0, stream>>>(ei, offsets, cursor, slot_tk, tk_slot);
  k_gateup<<<1536, 512, 0, stream>>>(xb, w1, w3, offsets, slot_tk, mtE, mtM0, nmt, act);
  k_down<<<1024, 512, 0, stream>>>(act, w2, offsets, mtE, mtM0, nmt, pout);
  k_combine<<<T_TOK, 256, 0, stream>>>(pout, tk_slot, wvp, out);
}